// Round 2
// baseline (330.303 us; speedup 1.0000x reference)
//
#include <hip/hip_runtime.h>
#include <math.h>

#define DIMD 1024
#define SEQ  2048
#define BATCH 8
#define ROWS (BATCH * SEQ)   // 16384

#define MF 1280              // folded cos-GEMM M (rows s=0..1279; need 0..1024; mult of 256)
#define KF 1152              // folded cos-GEMM K (t=0..1024 + zero pad to 18*64)

typedef __attribute__((ext_vector_type(8))) short bf16x8;
typedef __attribute__((ext_vector_type(4))) float f32x4;
typedef __attribute__((ext_vector_type(8))) unsigned short ushort8;

// ---------------- helpers ----------------
__device__ __forceinline__ unsigned short f2bf(float f) {
    unsigned u = __float_as_uint(f);
    unsigned r = (u + 0x7FFFu + ((u >> 16) & 1u)) >> 16;
    return (unsigned short)r;
}
__device__ __forceinline__ void gl_lds16(const void* g, void* l) {
    __builtin_amdgcn_global_load_lds(
        (const __attribute__((address_space(1))) unsigned int*)g,
        (__attribute__((address_space(3))) unsigned int*)l, 16, 0, 0);
}

// ---------------------------------------------------------------------------
// Precompute kernels
// ---------------------------------------------------------------------------

// Acos[s][t] = bf16(1024*cos(pi*((s*t)&2047)/1024)) for t<=1024, else 0.
__global__ __launch_bounds__(256) void build_acos(unsigned short* __restrict__ Acos) {
    int s = blockIdx.x;                       // 0..MF-1
    for (int t = threadIdx.x; t < KF; t += 256) {
        float c = 0.0f;
        if (t <= 1024) {
            int prod = (s * t) & (SEQ - 1);
            c = 1024.0f * cospif((float)prod * (1.0f / 1024.0f));
        }
        Acos[(size_t)s * KF + t] = f2bf(c);
    }
}

// Xe[n = b*1024+d][t] = bf16( x[b,t,rev(d)] + x[b,2048-t,rev(d)] ) (folded), 8192 x KF
__global__ __launch_bounds__(256) void build_xe(const float* __restrict__ x,
                                                unsigned short* __restrict__ Xe) {
    int lane = threadIdx.x & 63;
    int oct  = threadIdx.x >> 6;
    int n = blockIdx.x * 64 + lane;           // 0..8191
    int b = n >> 10, d = n & 1023;
    int rd = (DIMD - d) & (DIMD - 1);
    int t0 = blockIdx.y * 32 + oct * 8;       // 0..KF-8
    const float* xb = x + (size_t)b * SEQ * DIMD + rd;
    ushort8 tmp;
    #pragma unroll
    for (int j = 0; j < 8; ++j) {
        int t = t0 + j;
        float v;
        if (t == 0)          v = xb[0];
        else if (t < 1024)   v = xb[(size_t)t * DIMD] + xb[(size_t)(2048 - t) * DIMD];
        else if (t == 1024)  v = xb[(size_t)1024 * DIMD];
        else                 v = 0.0f;
        tmp[j] = f2bf(v);
    }
    *(ushort8*)&Xe[(size_t)n * KF + t0] = tmp;
}

// Wt[n][k] = bf16(W[k][n]),  1024 x 1024
__global__ __launch_bounds__(256) void pack_wt(const float* __restrict__ W,
                                               unsigned short* __restrict__ Wt) {
    int lane = threadIdx.x & 63;
    int oct = threadIdx.x >> 6;
    int n = blockIdx.x * 64 + lane;
    int k0 = blockIdx.y * 32 + oct * 8;
    ushort8 tmp;
    #pragma unroll
    for (int j = 0; j < 8; ++j) tmp[j] = f2bf(W[(size_t)(k0 + j) * DIMD + n]);
    *(ushort8*)&Wt[(size_t)n * DIMD + k0] = tmp;
}

// ---------------------------------------------------------------------------
// 8-phase 256x256 MFMA GEMM, single-barrier reg-double-buffered pipeline.
// C[M x N] = A[M x K] @ B^T[N x K] (bf16 in, f32 acc)
// 512 thr = 8 waves (2M x 4N); per-wave 128x64 out; BK=64; LDS 128 KiB (2 K-tile dbuf).
// LDS tile = 32 chunks of [8 rows][64 cols]; 16B-slot s of row r holds source
// col s^(r&7)  (XOR swizzle; measured 0 bank conflicts).
//
// NEW (R2): each phase body consumes frags loaded during the PREVIOUS phase
// (register double-buffer setA/setB) while issuing the next phase's ds_reads
// interleaved with its 16 MFMAs.  ONE barrier per phase; the only lgkm wait
// is lgkmcnt(0) at body end (covers this body's hoisted reads -> next body's
// frags are resident at entry; also upholds the region-reuse invariant).
//
// Body(p): [vmcnt(2) if p3/p7] ; STAGE(S_p) ; {read nxt ks0 | MFMA cur ks0 |
//          read nxt ks1 | MFMA cur ks1} ; lgkmcnt(0) ; barrier
//
// Region-safety derivation (per-body: stage region vs read regions, all disjoint;
// staged region's last frag-read was issued one body earlier and completed via
// that body's lgkmcnt(0)+barrier):
//   body  consume(buf,qm,qn)  reads-for-next      stage            fence
//   p0    P,0,0               P,0,1 (PA0,PB1)     Q.A1 <- t1       -
//   p1    P,0,1               P,1,0 (PA1,PB0)     Q.B1 <- t1       -
//   p2    P,1,0               P,1,1 (PA1,PB1)     P.A0 <- t2       -
//   p3    P,1,1               Q,0,0 (QA0,QB0)     P.B0 <- t2       vmcnt(2)
//   p4    Q,0,0               Q,0,1 (QA0,QB1)     P.A1 <- t2       -
//   p5    Q,0,1               Q,1,0 (QA1,QB0)     P.B1 <- t2       -
//   p6    Q,1,0               Q,1,1 (QA1,QB1)     Q.A0 <- t3       -
//   p7    Q,1,1               P,0,0 (PA0,PB0)     Q.B0 <- t3       vmcnt(2)
// vmcnt(2)@p3 start (before its stage): newest 2 outstanding = p2's PA0 pair;
//   everything older (Q<-t1: p6-,p7-,p0,p1) complete -> p3's hoisted Q reads safe.
// vmcnt(2)@p7 start: newest 2 = p6's QA0 pair; P<-t2 (p2..p5) complete ->
//   p7's hoisted P reads (next iter's t2) safe.
// Tail: clamped t2/t3 junk lands in regions whose hoisted reads are never
//   consumed (loop exits after p7); addresses stay in-bounds.
// MODE 0: F_f32 = acc (natural grid)
// MODE 1: h_bf16 = bf16(gelu(acc+bias))     [XCD swizzle, grid (4,64)]
// MODE 2: out_f32 = (acc+bias)*mask[row]    [XCD swizzle, grid (4,64)]
// ---------------------------------------------------------------------------
template <int MODE>
__global__ __launch_bounds__(512, 2) void gemm8p(const unsigned short* __restrict__ A,
                                                 const unsigned short* __restrict__ B,
                                                 int K, int lda, int ldb, int ldc,
                                                 const float* __restrict__ bias,
                                                 const float* __restrict__ mask,
                                                 void* __restrict__ outp) {
    __shared__ unsigned short As[2][256 * 64];   // 64 KiB
    __shared__ unsigned short Bs[2][256 * 64];   // 64 KiB

    const int tid  = threadIdx.x;
    const int lane = tid & 63;
    const int w    = tid >> 6;         // wave 0..7
    const int wm   = w >> 2;           // 0..1
    const int wn   = w & 3;            // 0..3
    const int fr   = lane & 15;
    const int quad = lane >> 4;
    const int sw   = fr & 7;

    const int st_row = lane >> 3;             // 0..7 within chunk
    const int st_col = ((lane & 7) ^ st_row) * 8;  // swizzled source element col

    int bx = blockIdx.x, by = blockIdx.y;
    if (MODE != 0) {
        // Bijective XCD swizzle for grid (4,64): XCD c gets m-tiles {8c..8c+7},
        // all 4 n-tiles -> per-XCD A working set 4 MB (fetched once chip-wide),
        // B (2 MB) L2-resident.
        int lin = bx + 4 * by;         // hardware linear id; XCD = lin & 7
        int c = lin & 7, r = lin >> 3; // r: 0..31
        by = c * 8 + (r >> 2);
        bx = r & 3;
    }
    const int m0 = by * 256;
    const int n0 = bx * 256;

    // staging: one region (16 chunks) per phase, 2 chunks (2 x gl_lds16) per wave.
    auto stageA = [&](int buf, int qm, int kt) {
        int kb = kt * 64 + st_col;
        int c0 = qm * 8 + w;
        int c1 = 16 + qm * 8 + w;
        gl_lds16(&A[(size_t)(m0 + c0 * 8 + st_row) * lda + kb], &As[buf][c0 * 512]);
        gl_lds16(&A[(size_t)(m0 + c1 * 8 + st_row) * lda + kb], &As[buf][c1 * 512]);
    };
    auto stageB = [&](int buf, int qn, int kt) {
        int kb = kt * 64 + st_col;
        int c0 = (w >> 1) * 8 + qn * 4 + (w & 1) * 2;
        int c1 = c0 + 1;
        gl_lds16(&B[(size_t)(n0 + c0 * 8 + st_row) * ldb + kb], &Bs[buf][c0 * 512]);
        gl_lds16(&B[(size_t)(n0 + c1 * 8 + st_row) * ldb + kb], &Bs[buf][c1 * 512]);
    };

    f32x4 acc[8][4] = {};

    // Register double-buffered fragments (two named sets; phases alternate).
    bf16x8 afA[4][2], bvA[2][2], afB[4][2], bvB[2][2];

#define READS(NAF, NBV, BUFR, QMR, QNR, KS)                                          \
    _Pragma("unroll") for (int i = 0; i < 4; ++i)                                    \
        NAF[i][KS] = *(const bf16x8*)&As[BUFR][(wm * 128 + QMR * 64 + i * 16 + fr) * 64 \
                                              + (((KS * 4 + quad) ^ sw) * 8)];       \
    _Pragma("unroll") for (int j = 0; j < 2; ++j)                                    \
        NBV[j][KS] = *(const bf16x8*)&Bs[BUFR][(wn * 64 + QNR * 32 + j * 16 + fr) * 64 \
                                              + (((KS * 4 + quad) ^ sw) * 8)];

#define MFMAS(CAF, CBV, QMC, QNC, KS)                                                \
    _Pragma("unroll") for (int i = 0; i < 4; ++i)                                    \
        _Pragma("unroll") for (int j = 0; j < 2; ++j)                                \
            acc[QMC * 4 + i][QNC * 2 + j] = __builtin_amdgcn_mfma_f32_16x16x32_bf16( \
                CAF[i][KS], CBV[j][KS], acc[QMC * 4 + i][QNC * 2 + j], 0, 0, 0);

#define PHASE(CAF, CBV, NAF, NBV, QMC, QNC, BUFR, QMR, QNR, STAGE, FENCE)            \
    {                                                                                \
        if (FENCE) asm volatile("s_waitcnt vmcnt(2)" ::: "memory");                  \
        STAGE;                                                                       \
        READS(NAF, NBV, BUFR, QMR, QNR, 0)                                           \
        __builtin_amdgcn_s_setprio(1);                                               \
        MFMAS(CAF, CBV, QMC, QNC, 0)                                                 \
        READS(NAF, NBV, BUFR, QMR, QNR, 1)                                           \
        MFMAS(CAF, CBV, QMC, QNC, 1)                                                 \
        __builtin_amdgcn_s_setprio(0);                                               \
        asm volatile("s_waitcnt lgkmcnt(0)" ::: "memory");                           \
        __builtin_amdgcn_s_barrier();                                                \
    }

    const int NT  = K >> 6;    // K-tiles (even: 16 or 18)
    const int NIT = NT >> 1;

    // Prologue: P <- t0 (4 regions), Q <- t1 first two regions; 12 loads issued.
    stageA(0, 0, 0); stageB(0, 0, 0); stageA(0, 1, 0); stageB(0, 1, 0);
    stageA(1, 0, 1); stageB(1, 0, 1);
    asm volatile("s_waitcnt vmcnt(4)" ::: "memory");   // P complete; Q.A0/B0 in flight
    __builtin_amdgcn_s_barrier();
    // Preload frags for p0 (set A <- P quadrant 0,0).
    READS(afA, bvA, 0, 0, 0, 0)
    READS(afA, bvA, 0, 0, 0, 1)
    asm volatile("s_waitcnt lgkmcnt(0)" ::: "memory");
    __builtin_amdgcn_s_barrier();

    for (int i = 0; i < NIT; ++i) {
        int t1 = 2 * i + 1;
        int t2 = 2 * i + 2; if (t2 >= NT) t2 = NT - 2;  // clamp: junk lands in
        int t3 = 2 * i + 3; if (t3 >= NT) t3 = NT - 2;  // never-consumed regions
        PHASE(afA, bvA, afB, bvB, 0, 0, 0, 0, 1, stageA(1, 1, t1), 0)   // p0
        PHASE(afB, bvB, afA, bvA, 0, 1, 0, 1, 0, stageB(1, 1, t1), 0)   // p1
        PHASE(afA, bvA, afB, bvB, 1, 0, 0, 1, 1, stageA(0, 0, t2), 0)   // p2
        PHASE(afB, bvB, afA, bvA, 1, 1, 1, 0, 0, stageB(0, 0, t2), 1)   // p3
        PHASE(afA, bvA, afB, bvB, 0, 0, 1, 0, 1, stageA(0, 1, t2), 0)   // p4
        PHASE(afB, bvB, afA, bvA, 0, 1, 1, 1, 0, stageB(0, 1, t2), 0)   // p5
        PHASE(afA, bvA, afB, bvB, 1, 0, 1, 1, 1, stageA(1, 0, t3), 0)   // p6
        PHASE(afB, bvB, afA, bvA, 1, 1, 0, 0, 0, stageB(1, 0, t3), 1)   // p7
    }
#undef PHASE
#undef MFMAS
#undef READS

    // epilogue: row = m0 + wm*128 + mi*16 + quad*4 + r ; col = n0 + wn*64 + nj*16 + fr
    #pragma unroll
    for (int mi = 0; mi < 8; ++mi) {
        int rowb = m0 + wm * 128 + mi * 16 + quad * 4;
        #pragma unroll
        for (int nj = 0; nj < 4; ++nj) {
            int col = n0 + wn * 64 + nj * 16 + fr;
            float bcol = (MODE != 0) ? bias[col] : 0.0f;
            #pragma unroll
            for (int r = 0; r < 4; ++r) {
                float v = acc[mi][nj][r];
                int row = rowb + r;
                if (MODE == 0) {
                    ((float*)outp)[(size_t)row * ldc + col] = v;
                } else if (MODE == 1) {
                    v += bcol;
                    v = 0.5f * v * (1.0f + erff(v * 0.70710678118654752f));
                    ((unsigned short*)outp)[(size_t)row * ldc + col] = f2bf(v);
                } else {
                    v += bcol;
                    v *= mask[row];
                    ((float*)outp)[(size_t)row * ldc + col] = v;
                }
            }
        }
    }
}

// ---------------------------------------------------------------------------
// LayerNorm pair: block (sp, b) reads F[sp] ONCE, handles rows s=sp and s=2048-sp.
// ---------------------------------------------------------------------------
__global__ __launch_bounds__(256) void ln_pair(const float* __restrict__ x,
                                               const float* __restrict__ F,
                                               const float* __restrict__ g,
                                               const float* __restrict__ beta,
                                               unsigned short* __restrict__ t) {
    const int sp = blockIdx.x;                // 0..1024
    const int b  = blockIdx.y;

    float4 fv = ((const float4*)(F + (size_t)sp * 8192 + (size_t)b * 1024))[threadIdx.x];
    float4 g4 = ((const float4*)g)[threadIdx.x];
    float4 b4 = ((const float4*)beta)[threadIdx.x];

    __shared__ float red[4];
    const int wave = threadIdx.x >> 6;
    const int lane = threadIdx.x & 63;

    const int nrows = (sp >= 1 && sp <= 1023) ? 2 : 1;
    for (int p = 0; p < nrows; ++p) {
        int s = p ? (2048 - sp) : sp;
        int row = b * SEQ + s;
        float4 xv = ((const float4*)(x + (size_t)row * DIMD))[threadIdx.x];
        float v0 = xv.x + fv.x, v1 = xv.y + fv.y, v2 = xv.z + fv.z, v3 = xv.w + fv.w;

        float sm = v0 + v1 + v2 + v3;
        #pragma unroll
        for (int off = 32; off > 0; off >>= 1) sm += __shfl_down(sm, off, 64);
        if (lane == 0) red[wave] = sm;
        __syncthreads();
        const float mean = (red[0] + red[1] + red[2] + red[3]) * (1.0f / DIMD);

        float dx0 = v0 - mean, dx1 = v1 - mean, dx2 = v2 - mean, dx3 = v3 - mean;
        float q = dx0 * dx0 + dx1 * dx1 + dx2 * dx2 + dx3 * dx3;
        __syncthreads();
        #pragma unroll
        for (int off = 32; off > 0; off >>= 1) q += __shfl_down(q, off, 64);
        if (lane == 0) red[wave] = q;
        __syncthreads();
        const float var = (red[0] + red[1] + red[2] + red[3]) * (1.0f / DIMD);
        const float rstd = rsqrtf(var + 1e-5f);

        ushort4 o;
        o.x = f2bf(dx0 * rstd * g4.x + b4.x);
        o.y = f2bf(dx1 * rstd * g4.y + b4.y);
        o.z = f2bf(dx2 * rstd * g4.z + b4.z);
        o.w = f2bf(dx3 * rstd * g4.w + b4.w);
        ((ushort4*)(t + (size_t)row * DIMD))[threadIdx.x] = o;
        __syncthreads();
    }
}

// ===========================================================================
// Fallback fp32 path (round-1 kernels) for small workspace
// ===========================================================================
#define BM 64
#define BN 64
#define BK 16

__global__ __launch_bounds__(256) void fft_cos_kernel(const float* __restrict__ x,
                                                      float* __restrict__ y) {
    __shared__ float tab[SEQ];
    __shared__ float As[BM][BK + 1];
    __shared__ float Bs[BK][BN + 1];
    const int tid = threadIdx.x;
    const int b = blockIdx.z;
    const int s0 = blockIdx.y * BM;
    const int n0 = blockIdx.x * BN;
    for (int i = tid; i < SEQ; i += 256) tab[i] = cospif((float)i * (1.0f / 1024.0f));
    const int tx = tid & 15;
    const int ty = tid >> 4;
    float acc[4][4] = {};
    const float* Xb = x + (size_t)b * SEQ * DIMD;
    for (int k0 = 0; k0 < SEQ; k0 += BK) {
        __syncthreads();
        for (int f = tid; f < BM * BK; f += 256) {
            int i = f / BK, k = f % BK;
            int prod = (s0 + i) * (k0 + k);
            As[i][k] = tab[prod & (SEQ - 1)];
        }
        for (int f = tid; f < BK * BN; f += 256) {
            int k = f / BN, j = f % BN;
            int d = n0 + j;
            int rd = (DIMD - d) & (DIMD - 1);
            Bs[k][j] = Xb[(size_t)(k0 + k) * DIMD + rd];
        }
        __syncthreads();
        #pragma unroll
        for (int k = 0; k < BK; ++k) {
            float a[4], bv[4];
            #pragma unroll
            for (int i = 0; i < 4; ++i) a[i] = As[ty * 4 + i][k];
            #pragma unroll
            for (int j = 0; j < 4; ++j) bv[j] = Bs[k][tx * 4 + j];
            #pragma unroll
            for (int i = 0; i < 4; ++i)
                #pragma unroll
                for (int j = 0; j < 4; ++j) acc[i][j] += a[i] * bv[j];
        }
    }
    #pragma unroll
    for (int i = 0; i < 4; ++i) {
        int s = s0 + ty * 4 + i;
        #pragma unroll
        for (int j = 0; j < 4; ++j) {
            int d = n0 + tx * 4 + j;
            y[((size_t)b * SEQ + s) * DIMD + d] = Xb[(size_t)s * DIMD + d] + 1024.0f * acc[i][j];
        }
    }
}

__global__ __launch_bounds__(256) void ln_kernel(float* __restrict__ y,
                                                 const float* __restrict__ g,
                                                 const float* __restrict__ beta) {
    const int row = blockIdx.x;
    float4* p = (float4*)(y + (size_t)row * DIMD);
    float4 v = p[threadIdx.x];
    __shared__ float red[4];
    const int wave = threadIdx.x >> 6;
    const int lane = threadIdx.x & 63;
    float s = v.x + v.y + v.z + v.w;
    #pragma unroll
    for (int off = 32; off > 0; off >>= 1) s += __shfl_down(s, off, 64);
    if (lane == 0) red[wave] = s;
    __syncthreads();
    const float mean = (red[0] + red[1] + red[2] + red[3]) * (1.0f / DIMD);
    float dx0 = v.x - mean, dx1 = v.y - mean, dx2 = v.z - mean, dx3 = v.w - mean;
    float q = dx0 * dx0 + dx1 * dx1 + dx2 * dx2 + dx3 * dx3;
    __syncthreads();
    #pragma unroll
    for (int off = 32; off > 0; off >>= 1) q += __shfl_down(q, off, 64);
    if (lane == 0) red[wave] = q;
    __syncthreads();
    const float var = (red[0] + red[1] + red[2] + red[3]) * (1.0f / DIMD);
    const float rstd = rsqrtf(var + 1e-5f);
    float4 g4 = ((const float4*)g)[threadIdx.x];
    float4 b4 = ((const float4*)beta)[threadIdx.x];
    float4 o;
    o.x = dx0 * rstd * g4.x + b4.x;
    o.y = dx1 * rstd * g4.y + b4.y;
    o.z = dx2 * rstd * g4.z + b4.z;
    o.w = dx3 * rstd * g4.w + b4.w;
    p[threadIdx.x] = o;
}

template <int MODE>
__global__ __launch_bounds__(256) void ff_gemm(const float* __restrict__ A,
                                               const float* __restrict__ W,
                                               const float* __restrict__ bias,
                                               const float* __restrict__ mask,
                                               float* __restrict__ out) {
    __shared__ float As[BM][BK + 1];
    __shared__ float Bs[BK][BN + 1];
    const int tid = threadIdx.x;
    const int tx = tid & 15;
    const int ty = tid >> 4;
    const int m0 = blockIdx.y * BM;
    const int n0 = blockIdx.x * BN;
    float acc[4][4] = {};
    for (int k0 = 0; k0 < DIMD; k0 += BK) {
        __syncthreads();
        for (int f = tid; f < BM * BK; f += 256) {
            int i = f / BK, k = f % BK;
            As[i][k] = A[(size_t)(m0 + i) * DIMD + k0 + k];
        }
        for (int f = tid; f < BK * BN; f += 256) {
            int k = f / BN, j = f % BN;
            Bs[k][j] = W[(size_t)(k0 + k) * DIMD + n0 + j];
        }
        __syncthreads();
        #pragma unroll
        for (int k = 0; k < BK; ++k) {
            float a[4], bv[4];
            #pragma unroll
            for (int i = 0; i < 4; ++i) a[i] = As[ty * 4 + i][k];
            #pragma unroll
            for (int j = 0; j < 4; ++j) bv[j] = Bs[k][tx * 4 + j];
            #pragma unroll
            for (int i = 0; i < 4; ++i)
                #pragma unroll
                for (int j = 0; j < 4; ++j) acc[i][j] += a[i] * bv[j];
        }
    }
    #pragma unroll
    for (int i = 0; i < 4; ++i) {
        int m = m0 + ty * 4 + i;
        float mk = (MODE == 1) ? mask[m] : 1.0f;
        #pragma unroll
        for (int j = 0; j < 4; ++j) {
            int n = n0 + tx * 4 + j;
            float v = acc[i][j] + bias[n];
            if (MODE == 0) v = 0.5f * v * (1.0f + erff(v * 0.70710678118654752f));
            else v *= mk;
            out[(size_t)m * DIMD + n] = v;
        }
    }
}

// ===========================================================================
extern "C" void kernel_launch(void* const* d_in, const int* in_sizes, int n_in,
                              void* d_out, int out_size, void* d_ws, size_t ws_size,
                              hipStream_t stream) {
    const float* x    = (const float*)d_in[0];
    const float* mask = (const float*)d_in[1];
    const float* ln_g = (const float*)d_in[2];
    const float* ln_b = (const float*)d_in[3];
    const float* w1   = (const float*)d_in[4];
    const float* b1   = (const float*)d_in[5];
    const float* w2   = (const float*)d_in[6];
    const float* b2   = (const float*)d_in[7];
    float* out = (float*)d_out;

    const size_t MB = 1024 * 1024;
    dim3 blk(256);
    dim3 blk512(512);

    if (ws_size >= 70 * MB) {
        char* w = (char*)d_ws;
        unsigned short* Acos = (unsigned short*)w;             // @0,  2.95 MB (dead after cos gemm)
        unsigned short* Xe   = (unsigned short*)(w + 4 * MB);  // @4,  18.9 MB (dead after cos gemm)
        unsigned short* t    = (unsigned short*)(w + 32 * MB); // @32, 32 MB
        unsigned short* h    = (unsigned short*)w;             // @0,  32 MB (over Acos+Xe after ln)
        unsigned short* W1t  = (unsigned short*)(w + 64 * MB); // 2 MB
        unsigned short* W2t  = (unsigned short*)(w + 66 * MB); // 2 MB
        float* F = (float*)d_out;                              // 40 MB scratch in d_out

        build_acos<<<dim3(MF), blk, 0, stream>>>(Acos);
        build_xe<<<dim3(8192 / 64, KF / 32), blk, 0, stream>>>(x, Xe);
        pack_wt<<<dim3(1024 / 64, 1024 / 32), blk, 0, stream>>>(w1, W1t);
        pack_wt<<<dim3(1024 / 64, 1024 / 32), blk, 0, stream>>>(w2, W2t);

        // F[s][n] = sum_t Acos[s][t] * Xe[n][t]   (scale folded into Acos)
        gemm8p<0><<<dim3(8192 / 256, MF / 256), blk512, 0, stream>>>(
            Acos, Xe, KF, KF, KF, 8192, nullptr, nullptr, F);
        // t = bf16(LayerNorm(x + F[mirror]))  — one F-row read per pair
        ln_pair<<<dim3(1025, BATCH), blk, 0, stream>>>(x, F, ln_g, ln_b, t);
        // h = bf16(gelu(t @ W1 + b1))
        gemm8p<1><<<dim3(1024 / 256, ROWS / 256), blk512, 0, stream>>>(
            t, W1t, 1024, 1024, 1024, 1024, b1, nullptr, h);
        // out = (h @ W2 + b2) * mask
        gemm8p<2><<<dim3(1024 / 256, ROWS / 256), blk512, 0, stream>>>(
            h, W2t, 1024, 1024, 1024, 1024, b2, mask, out);
    } else {
        // fp32 fallback (round-1 path)
        float* yf = (float*)d_ws;
        const size_t bufBytes = (size_t)ROWS * DIMD * sizeof(float);
        fft_cos_kernel<<<dim3(DIMD / BN, SEQ / BM, BATCH), blk, 0, stream>>>(x, yf);
        ln_kernel<<<dim3(ROWS), blk, 0, stream>>>(yf, ln_g, ln_b);
        ff_gemm<0><<<dim3(DIMD / BN, ROWS / BM), blk, 0, stream>>>(yf, w1, b1, nullptr, out);
        ff_gemm<1><<<dim3(DIMD / BN, ROWS / BM), blk, 0, stream>>>(out, w2, b2, mask, yf);
        hipMemcpyAsync(d_out, yf, bufBytes, hipMemcpyDeviceToDevice, stream);
    }
}

// Round 4
// 307.907 us; speedup vs baseline: 1.0727x; 1.0727x over previous
//
#include <hip/hip_runtime.h>
#include <math.h>

#define DIMD 1024
#define SEQ  2048
#define BATCH 8
#define ROWS (BATCH * SEQ)   // 16384

#define MF 1280              // folded cos-GEMM M (rows s=0..1279; need 0..1024; mult of 256)
#define KF 1088              // folded cos-GEMM K (t=0..1024 + pad to 17*64)

typedef __attribute__((ext_vector_type(8))) short bf16x8;
typedef __attribute__((ext_vector_type(4))) float f32x4;
typedef __attribute__((ext_vector_type(16))) float f32x16;
typedef __attribute__((ext_vector_type(8))) unsigned short ushort8;

// ---------------- helpers ----------------
__device__ __forceinline__ unsigned short f2bf(float f) {
    unsigned u = __float_as_uint(f);
    unsigned r = (u + 0x7FFFu + ((u >> 16) & 1u)) >> 16;
    return (unsigned short)r;
}
__device__ __forceinline__ void gl_lds16(const void* g, void* l) {
    __builtin_amdgcn_global_load_lds(
        (const __attribute__((address_space(1))) unsigned int*)g,
        (__attribute__((address_space(3))) unsigned int*)l, 16, 0, 0);
}

// ---------------------------------------------------------------------------
// Precompute kernels
// ---------------------------------------------------------------------------

// Acos[s][t] = bf16(1024*cos(pi*((s*t)&2047)/1024)) for t<=1024, else 0.
__global__ __launch_bounds__(256) void build_acos(unsigned short* __restrict__ Acos) {
    int s = blockIdx.x;                       // 0..MF-1
    for (int t = threadIdx.x; t < KF; t += 256) {
        float c = 0.0f;
        if (t <= 1024) {
            int prod = (s * t) & (SEQ - 1);
            c = 1024.0f * cospif((float)prod * (1.0f / 1024.0f));
        }
        Acos[(size_t)s * KF + t] = f2bf(c);
    }
}

// Xe[n = b*1024+d][t] = bf16( x[b,t,rev(d)] + x[b,2048-t,rev(d)] ) (folded), 8192 x KF
__global__ __launch_bounds__(256) void build_xe(const float* __restrict__ x,
                                                unsigned short* __restrict__ Xe) {
    int lane = threadIdx.x & 63;
    int oct  = threadIdx.x >> 6;
    int n = blockIdx.x * 64 + lane;           // 0..8191
    int b = n >> 10, d = n & 1023;
    int rd = (DIMD - d) & (DIMD - 1);
    int t0 = blockIdx.y * 32 + oct * 8;       // 0..KF-8
    const float* xb = x + (size_t)b * SEQ * DIMD + rd;
    ushort8 tmp;
    #pragma unroll
    for (int j = 0; j < 8; ++j) {
        int t = t0 + j;
        float v;
        if (t == 0)          v = xb[0];
        else if (t < 1024)   v = xb[(size_t)t * DIMD] + xb[(size_t)(2048 - t) * DIMD];
        else if (t == 1024)  v = xb[(size_t)1024 * DIMD];
        else                 v = 0.0f;
        tmp[j] = f2bf(v);
    }
    *(ushort8*)&Xe[(size_t)n * KF + t0] = tmp;
}

// Wt[n][k] = bf16(W[k][n]),  1024 x 1024
__global__ __launch_bounds__(256) void pack_wt(const float* __restrict__ W,
                                               unsigned short* __restrict__ Wt) {
    int lane = threadIdx.x & 63;
    int oct = threadIdx.x >> 6;
    int n = blockIdx.x * 64 + lane;
    int k0 = blockIdx.y * 32 + oct * 8;
    ushort8 tmp;
    #pragma unroll
    for (int j = 0; j < 8; ++j) tmp[j] = f2bf(W[(size_t)(k0 + j) * DIMD + n]);
    *(ushort8*)&Wt[(size_t)n * DIMD + k0] = tmp;
}

// ---------------------------------------------------------------------------
// 256x256 MFMA GEMM on 32x32x16 bf16, one barrier per K-tile.
// C[M x N] = A[M x K] @ B^T[N x K] (bf16 in, f32 acc)
// 512 thr = 8 waves (2M x 4N); per-wave 128x64 out as 4x2 grid of 32x32 blocks;
// BK=64 (4 ksteps of K=16); LDS 128 KiB (2 K-tile dbuf).
// LDS tile = 32 chunks of [8 rows][64 cols]; 16B-slot s of row r holds source
// col-group s^(r&7) (XOR swizzle; measured 0 bank conflicts).
//
// R4 FIX: R3's cross-barrier prefetch read buf[cur^1] before the barrier;
// vmcnt(0) is PER-WAVE, so chunks staged by other waves in the same barrier
// interval were not guaranteed complete -> race (absmax 0.186). Now every
// read of a staged buffer is separated from its staging by {each wave's
// vmcnt(0)} + barrier. One barrier per K-tile:
//   READ(k0)  <- buf[cur], globally complete as of previous barrier
//   stage(cur^1, t+1)      ; 8 gl_lds16
//   READ(k1) MFMA(k0)
//   READ(k2) MFMA(k1)
//   READ(k3) MFMA(k2)
//   MFMA(k3)
//   vmcnt(0) lgkmcnt(0)    ; my stages + my reads drained
//   barrier                ; => all waves' stages/reads drained
// Tail: t=NT-1 restages tile NT-1 into the dead buffer (in-bounds, never read).
//
// Fragment mapping: A/B row(col) = lane&31, k-group = lane>>5 (8 contiguous);
// any consistent bijective k-permutation of A and B is sum-invariant.
// C/D: col = lane&31, row = (reg&3) + 8*(reg>>2) + 4*(lane>>5)  [m74/m101]
// MODE 0: F_f32 = acc (natural grid)
// MODE 1: h_bf16 = bf16(gelu(acc+bias))     [XCD swizzle, grid (4,64)]
// MODE 2: out_f32 = (acc+bias)*mask[row]    [XCD swizzle, grid (4,64)]
// ---------------------------------------------------------------------------
template <int MODE>
__global__ __launch_bounds__(512, 2) void gemm32(const unsigned short* __restrict__ A,
                                                 const unsigned short* __restrict__ B,
                                                 int K, int lda, int ldb, int ldc,
                                                 const float* __restrict__ bias,
                                                 const float* __restrict__ mask,
                                                 void* __restrict__ outp) {
    __shared__ unsigned short As[2][256 * 64];   // 64 KiB
    __shared__ unsigned short Bs[2][256 * 64];   // 64 KiB

    const int tid  = threadIdx.x;
    const int lane = tid & 63;
    const int w    = tid >> 6;         // wave 0..7
    const int wm   = w >> 2;           // 0..1
    const int wn   = w & 3;            // 0..3
    const int r31  = lane & 31;
    const int hl   = lane >> 5;        // k-group select
    const int sw   = lane & 7;         // swizzle bits (row&7 for all our rows)

    const int st_row = lane >> 3;                  // 0..7 within chunk
    const int st_col = ((lane & 7) ^ st_row) * 8;  // swizzled source element col

    int bx = blockIdx.x, by = blockIdx.y;
    if (MODE != 0) {
        // Bijective XCD swizzle for grid (4,64): XCD c gets m-tiles {8c..8c+7},
        // all 4 n-tiles -> per-XCD A working set 4 MB, B (2 MB) L2-resident.
        int lin = bx + 4 * by;         // hardware linear id; XCD = lin & 7
        int c = lin & 7, r = lin >> 3; // r: 0..31
        by = c * 8 + (r >> 2);
        bx = r & 3;
    }
    const int m0 = by * 256;
    const int n0 = bx * 256;

    const int rA = wm * 128 + r31;     // A row base within tile (row&7 == sw)
    const int rB = wn * 64 + r31;      // B row base within tile

    // staging: 32 A-chunks + 32 B-chunks per K-tile; 4+4 per wave.
    auto stage = [&](int buf, int kt) {
        int kb = kt * 64 + st_col;
        #pragma unroll
        for (int c = 0; c < 4; ++c) {
            int ch = w + c * 8;        // 0..31 unique across waves
            gl_lds16(&A[(size_t)(m0 + ch * 8 + st_row) * lda + kb], &As[buf][ch * 512]);
            gl_lds16(&B[(size_t)(n0 + ch * 8 + st_row) * ldb + kb], &Bs[buf][ch * 512]);
        }
    };

    f32x16 acc[4][2] = {};
    bf16x8 a0[4], b0[2], a1[4], b1[2];

#define READK(SA, SB, PA, PB, KK)                                                    \
    {                                                                                \
        const int so_ = ((((KK) * 2) + hl) ^ sw) * 8;                                \
        _Pragma("unroll") for (int bi = 0; bi < 4; ++bi)                             \
            SA[bi] = *(const bf16x8*)&(PA)[(rA + bi * 32) * 64 + so_];               \
        _Pragma("unroll") for (int bj = 0; bj < 2; ++bj)                             \
            SB[bj] = *(const bf16x8*)&(PB)[(rB + bj * 32) * 64 + so_];               \
    }

#define MFMAK(SA, SB)                                                                \
    __builtin_amdgcn_s_setprio(1);                                                   \
    _Pragma("unroll") for (int bi = 0; bi < 4; ++bi)                                 \
        _Pragma("unroll") for (int bj = 0; bj < 2; ++bj)                             \
            acc[bi][bj] = __builtin_amdgcn_mfma_f32_32x32x16_bf16(                   \
                SA[bi], SB[bj], acc[bi][bj], 0, 0, 0);                               \
    __builtin_amdgcn_s_setprio(0);

    const int NT = K >> 6;   // K-tiles (16 or 17)

    // Prologue: stage tile 0; all waves drain own loads, then barrier =>
    // buffer 0 globally complete for everyone.
    stage(0, 0);
    asm volatile("s_waitcnt vmcnt(0)" ::: "memory");
    __builtin_amdgcn_s_barrier();

    int cur = 0;
    for (int t = 0; t < NT; ++t) {
        const unsigned short* pa = &As[cur][0];
        const unsigned short* pb = &Bs[cur][0];
        int nk = (t + 1 < NT) ? t + 1 : NT - 1;   // tail: restage (dead, in-bounds)
        READK(a0, b0, pa, pb, 0)            // buf[cur] complete since last barrier
        stage(cur ^ 1, nk);
        READK(a1, b1, pa, pb, 1)
        MFMAK(a0, b0)                       // k0
        READK(a0, b0, pa, pb, 2)
        MFMAK(a1, b1)                       // k1
        READK(a1, b1, pa, pb, 3)
        MFMAK(a0, b0)                       // k2
        MFMAK(a1, b1)                       // k3
        asm volatile("s_waitcnt vmcnt(0) lgkmcnt(0)" ::: "memory");
        __builtin_amdgcn_s_barrier();
        cur ^= 1;
    }
#undef MFMAK
#undef READK

    // epilogue: row = m0 + wm*128 + bi*32 + (reg&3) + 8*(reg>>2) + 4*hl
    //           col = n0 + wn*64 + bj*32 + r31
    #pragma unroll
    for (int bi = 0; bi < 4; ++bi) {
        int rowb = m0 + wm * 128 + bi * 32 + 4 * hl;
        #pragma unroll
        for (int bj = 0; bj < 2; ++bj) {
            int col = n0 + wn * 64 + bj * 32 + r31;
            float bcol = (MODE != 0) ? bias[col] : 0.0f;
            #pragma unroll
            for (int r = 0; r < 16; ++r) {
                float v = acc[bi][bj][r];
                int row = rowb + (r & 3) + 8 * (r >> 2);
                if (MODE == 0) {
                    ((float*)outp)[(size_t)row * ldc + col] = v;
                } else if (MODE == 1) {
                    v += bcol;
                    v = 0.5f * v * (1.0f + erff(v * 0.70710678118654752f));
                    ((unsigned short*)outp)[(size_t)row * ldc + col] = f2bf(v);
                } else {
                    v += bcol;
                    v *= mask[row];
                    ((float*)outp)[(size_t)row * ldc + col] = v;
                }
            }
        }
    }
}

// ---------------------------------------------------------------------------
// LayerNorm pair: block (sp, b) reads F[sp] ONCE, handles rows s=sp and s=2048-sp.
// ---------------------------------------------------------------------------
__global__ __launch_bounds__(256) void ln_pair(const float* __restrict__ x,
                                               const float* __restrict__ F,
                                               const float* __restrict__ g,
                                               const float* __restrict__ beta,
                                               unsigned short* __restrict__ t) {
    const int sp = blockIdx.x;                // 0..1024
    const int b  = blockIdx.y;

    float4 fv = ((const float4*)(F + (size_t)sp * 8192 + (size_t)b * 1024))[threadIdx.x];
    float4 g4 = ((const float4*)g)[threadIdx.x];
    float4 b4 = ((const float4*)beta)[threadIdx.x];

    __shared__ float red[4];
    const int wave = threadIdx.x >> 6;
    const int lane = threadIdx.x & 63;

    const int nrows = (sp >= 1 && sp <= 1023) ? 2 : 1;
    for (int p = 0; p < nrows; ++p) {
        int s = p ? (2048 - sp) : sp;
        int row = b * SEQ + s;
        float4 xv = ((const float4*)(x + (size_t)row * DIMD))[threadIdx.x];
        float v0 = xv.x + fv.x, v1 = xv.y + fv.y, v2 = xv.z + fv.z, v3 = xv.w + fv.w;

        float sm = v0 + v1 + v2 + v3;
        #pragma unroll
        for (int off = 32; off > 0; off >>= 1) sm += __shfl_down(sm, off, 64);
        if (lane == 0) red[wave] = sm;
        __syncthreads();
        const float mean = (red[0] + red[1] + red[2] + red[3]) * (1.0f / DIMD);

        float dx0 = v0 - mean, dx1 = v1 - mean, dx2 = v2 - mean, dx3 = v3 - mean;
        float q = dx0 * dx0 + dx1 * dx1 + dx2 * dx2 + dx3 * dx3;
        __syncthreads();
        #pragma unroll
        for (int off = 32; off > 0; off >>= 1) q += __shfl_down(q, off, 64);
        if (lane == 0) red[wave] = q;
        __syncthreads();
        const float var = (red[0] + red[1] + red[2] + red[3]) * (1.0f / DIMD);
        const float rstd = rsqrtf(var + 1e-5f);

        ushort4 o;
        o.x = f2bf(dx0 * rstd * g4.x + b4.x);
        o.y = f2bf(dx1 * rstd * g4.y + b4.y);
        o.z = f2bf(dx2 * rstd * g4.z + b4.z);
        o.w = f2bf(dx3 * rstd * g4.w + b4.w);
        ((ushort4*)(t + (size_t)row * DIMD))[threadIdx.x] = o;
        __syncthreads();
    }
}

// ===========================================================================
// Fallback fp32 path (round-1 kernels) for small workspace
// ===========================================================================
#define BM 64
#define BN 64
#define BK 16

__global__ __launch_bounds__(256) void fft_cos_kernel(const float* __restrict__ x,
                                                      float* __restrict__ y) {
    __shared__ float tab[SEQ];
    __shared__ float As[BM][BK + 1];
    __shared__ float Bs[BK][BN + 1];
    const int tid = threadIdx.x;
    const int b = blockIdx.z;
    const int s0 = blockIdx.y * BM;
    const int n0 = blockIdx.x * BN;
    for (int i = tid; i < SEQ; i += 256) tab[i] = cospif((float)i * (1.0f / 1024.0f));
    const int tx = tid & 15;
    const int ty = tid >> 4;
    float acc[4][4] = {};
    const float* Xb = x + (size_t)b * SEQ * DIMD;
    for (int k0 = 0; k0 < SEQ; k0 += BK) {
        __syncthreads();
        for (int f = tid; f < BM * BK; f += 256) {
            int i = f / BK, k = f % BK;
            int prod = (s0 + i) * (k0 + k);
            As[i][k] = tab[prod & (SEQ - 1)];
        }
        for (int f = tid; f < BK * BN; f += 256) {
            int k = f / BN, j = f % BN;
            int d = n0 + j;
            int rd = (DIMD - d) & (DIMD - 1);
            Bs[k][j] = Xb[(size_t)(k0 + k) * DIMD + rd];
        }
        __syncthreads();
        #pragma unroll
        for (int k = 0; k < BK; ++k) {
            float a[4], bv[4];
            #pragma unroll
            for (int i = 0; i < 4; ++i) a[i] = As[ty * 4 + i][k];
            #pragma unroll
            for (int j = 0; j < 4; ++j) bv[j] = Bs[k][tx * 4 + j];
            #pragma unroll
            for (int i = 0; i < 4; ++i)
                #pragma unroll
                for (int j = 0; j < 4; ++j) acc[i][j] += a[i] * bv[j];
        }
    }
    #pragma unroll
    for (int i = 0; i < 4; ++i) {
        int s = s0 + ty * 4 + i;
        #pragma unroll
        for (int j = 0; j < 4; ++j) {
            int d = n0 + tx * 4 + j;
            y[((size_t)b * SEQ + s) * DIMD + d] = Xb[(size_t)s * DIMD + d] + 1024.0f * acc[i][j];
        }
    }
}

__global__ __launch_bounds__(256) void ln_kernel(float* __restrict__ y,
                                                 const float* __restrict__ g,
                                                 const float* __restrict__ beta) {
    const int row = blockIdx.x;
    float4* p = (float4*)(y + (size_t)row * DIMD);
    float4 v = p[threadIdx.x];
    __shared__ float red[4];
    const int wave = threadIdx.x >> 6;
    const int lane = threadIdx.x & 63;
    float s = v.x + v.y + v.z + v.w;
    #pragma unroll
    for (int off = 32; off > 0; off >>= 1) s += __shfl_down(s, off, 64);
    if (lane == 0) red[wave] = s;
    __syncthreads();
    const float mean = (red[0] + red[1] + red[2] + red[3]) * (1.0f / DIMD);
    float dx0 = v.x - mean, dx1 = v.y - mean, dx2 = v.z - mean, dx3 = v.w - mean;
    float q = dx0 * dx0 + dx1 * dx1 + dx2 * dx2 + dx3 * dx3;
    __syncthreads();
    #pragma unroll
    for (int off = 32; off > 0; off >>= 1) q += __shfl_down(q, off, 64);
    if (lane == 0) red[wave] = q;
    __syncthreads();
    const float var = (red[0] + red[1] + red[2] + red[3]) * (1.0f / DIMD);
    const float rstd = rsqrtf(var + 1e-5f);
    float4 g4 = ((const float4*)g)[threadIdx.x];
    float4 b4 = ((const float4*)beta)[threadIdx.x];
    float4 o;
    o.x = dx0 * rstd * g4.x + b4.x;
    o.y = dx1 * rstd * g4.y + b4.y;
    o.z = dx2 * rstd * g4.z + b4.z;
    o.w = dx3 * rstd * g4.w + b4.w;
    p[threadIdx.x] = o;
}

template <int MODE>
__global__ __launch_bounds__(256) void ff_gemm(const float* __restrict__ A,
                                               const float* __restrict__ W,
                                               const float* __restrict__ bias,
                                               const float* __restrict__ mask,
                                               float* __restrict__ out) {
    __shared__ float As[BM][BK + 1];
    __shared__ float Bs[BK][BN + 1];
    const int tid = threadIdx.x;
    const int tx = tid & 15;
    const int ty = tid >> 4;
    const int m0 = blockIdx.y * BM;
    const int n0 = blockIdx.x * BN;
    float acc[4][4] = {};
    for (int k0 = 0; k0 < DIMD; k0 += BK) {
        __syncthreads();
        for (int f = tid; f < BM * BK; f += 256) {
            int i = f / BK, k = f % BK;
            As[i][k] = A[(size_t)(m0 + i) * DIMD + k0 + k];
        }
        for (int f = tid; f < BK * BN; f += 256) {
            int k = f / BN, j = f % BN;
            Bs[k][j] = W[(size_t)(k0 + k) * DIMD + n0 + j];
        }
        __syncthreads();
        #pragma unroll
        for (int k = 0; k < BK; ++k) {
            float a[4], bv[4];
            #pragma unroll
            for (int i = 0; i < 4; ++i) a[i] = As[ty * 4 + i][k];
            #pragma unroll
            for (int j = 0; j < 4; ++j) bv[j] = Bs[k][tx * 4 + j];
            #pragma unroll
            for (int i = 0; i < 4; ++i)
                #pragma unroll
                for (int j = 0; j < 4; ++j) acc[i][j] += a[i] * bv[j];
        }
    }
    #pragma unroll
    for (int i = 0; i < 4; ++i) {
        int m = m0 + ty * 4 + i;
        float mk = (MODE == 1) ? mask[m] : 1.0f;
        #pragma unroll
        for (int j = 0; j < 4; ++j) {
            int n = n0 + tx * 4 + j;
            float v = acc[i][j] + bias[n];
            if (MODE == 0) v = 0.5f * v * (1.0f + erff(v * 0.70710678118654752f));
            else v *= mk;
            out[(size_t)m * DIMD + n] = v;
        }
    }
}

// ===========================================================================
extern "C" void kernel_launch(void* const* d_in, const int* in_sizes, int n_in,
                              void* d_out, int out_size, void* d_ws, size_t ws_size,
                              hipStream_t stream) {
    const float* x    = (const float*)d_in[0];
    const float* mask = (const float*)d_in[1];
    const float* ln_g = (const float*)d_in[2];
    const float* ln_b = (const float*)d_in[3];
    const float* w1   = (const float*)d_in[4];
    const float* b1   = (const float*)d_in[5];
    const float* w2   = (const float*)d_in[6];
    const float* b2   = (const float*)d_in[7];
    float* out = (float*)d_out;

    const size_t MB = 1024 * 1024;
    dim3 blk(256);
    dim3 blk512(512);

    if (ws_size >= 70 * MB) {
        char* w = (char*)d_ws;
        unsigned short* Acos = (unsigned short*)w;             // @0,  2.8 MB (dead after cos gemm)
        unsigned short* Xe   = (unsigned short*)(w + 4 * MB);  // @4,  17.8 MB (dead after cos gemm)
        unsigned short* t    = (unsigned short*)(w + 32 * MB); // @32, 32 MB
        unsigned short* h    = (unsigned short*)w;             // @0,  32 MB (over Acos+Xe after ln)
        unsigned short* W1t  = (unsigned short*)(w + 64 * MB); // 2 MB
        unsigned short* W2t  = (unsigned short*)(w + 66 * MB); // 2 MB
        float* F = (float*)d_out;                              // 40 MB scratch in d_out

        build_acos<<<dim3(MF), blk, 0, stream>>>(Acos);
        build_xe<<<dim3(8192 / 64, KF / 32), blk, 0, stream>>>(x, Xe);
        pack_wt<<<dim3(1024 / 64, 1024 / 32), blk, 0, stream>>>(w1, W1t);
        pack_wt<<<dim3(1024 / 64, 1024 / 32), blk, 0, stream>>>(w2, W2t);

        // F[s][n] = sum_t Acos[s][t] * Xe[n][t]   (scale folded into Acos)
        gemm32<0><<<dim3(8192 / 256, MF / 256), blk512, 0, stream>>>(
            Acos, Xe, KF, KF, KF, 8192, nullptr, nullptr, F);
        // t = bf16(LayerNorm(x + F[mirror]))  — one F-row read per pair
        ln_pair<<<dim3(1025, BATCH), blk, 0, stream>>>(x, F, ln_g, ln_b, t);
        // h = bf16(gelu(t @ W1 + b1))
        gemm32<1><<<dim3(1024 / 256, ROWS / 256), blk512, 0, stream>>>(
            t, W1t, 1024, 1024, 1024, 1024, b1, nullptr, h);
        // out = (h @ W2 + b2) * mask
        gemm32<2><<<dim3(1024 / 256, ROWS / 256), blk512, 0, stream>>>(
            h, W2t, 1024, 1024, 1024, 1024, b2, mask, out);
    } else {
        // fp32 fallback (round-1 path)
        float* yf = (float*)d_ws;
        const size_t bufBytes = (size_t)ROWS * DIMD * sizeof(float);
        fft_cos_kernel<<<dim3(DIMD / BN, SEQ / BM, BATCH), blk, 0, stream>>>(x, yf);
        ln_kernel<<<dim3(ROWS), blk, 0, stream>>>(yf, ln_g, ln_b);
        ff_gemm<0><<<dim3(DIMD / BN, ROWS / BM), blk, 0, stream>>>(yf, w1, b1, nullptr, out);
        ff_gemm<1><<<dim3(DIMD / BN, ROWS / BM), blk, 0, stream>>>(out, w2, b2, mask, yf);
        hipMemcpyAsync(d_out, yf, bufBytes, hipMemcpyDeviceToDevice, stream);
    }
}